// Round 1
// baseline (443.075 us; speedup 1.0000x reference)
//
#include <hip/hip_runtime.h>

typedef unsigned short u16;
typedef unsigned int   u32;
typedef __bf16 bf16;
typedef bf16  bf16x8 __attribute__((ext_vector_type(8)));
typedef float f32x4  __attribute__((ext_vector_type(4)));

__device__ __forceinline__ u16 bf16u(float f) {
    u32 x = __builtin_bit_cast(u32, f);
    x += 0x7fffu + ((x >> 16) & 1u);   // RNE
    return (u16)(x >> 16);
}

__device__ __forceinline__ void gl_lds16(const void* g, void* l) {
    __builtin_amdgcn_global_load_lds(
        (const __attribute__((address_space(1))) u32*)g,
        (__attribute__((address_space(3))) u32*)l, 16, 0, 0);
}

// ---------------- fp32 -> bf16 convert (vectorized) ----------------
__global__ __launch_bounds__(256) void cvt_x_kernel(const float4* __restrict__ in,
                                                    ushort4* __restrict__ out, int n4) {
    int i = blockIdx.x * 256 + threadIdx.x;
    if (i >= n4) return;
    float4 f = in[i];
    ushort4 o;
    o.x = bf16u(f.x); o.y = bf16u(f.y); o.z = bf16u(f.z); o.w = bf16u(f.w);
    out[i] = o;
}

// ---------------- fp32 W[rows][cols] -> bf16 W^T[cols][rows] ----------------
__global__ __launch_bounds__(256) void transp_kernel(const float* __restrict__ W,
                                                     u16* __restrict__ WT,
                                                     int rows, int cols) {
    __shared__ float t[32][33];
    int bx = blockIdx.x * 32, by = blockIdx.y * 32;
    int x = threadIdx.x & 31, y = threadIdx.x >> 5;   // y in 0..7
#pragma unroll
    for (int i = 0; i < 32; i += 8)
        t[y + i][x] = W[(size_t)(by + y + i) * cols + bx + x];
    __syncthreads();
#pragma unroll
    for (int i = 0; i < 32; i += 8)
        WT[(size_t)(bx + y + i) * rows + by + x] = bf16u(t[x][y + i]);
}

// ---------------- bf16 GEMM: C[M][N] = A[M][K] * BT[N][K]^T ----------------
// mode 0: bf16 out, plain.  mode 1: bf16 out with fused RoPE (per-64 head dim).
// mode 2: fp32 out.
#define GBK 32
__global__ __launch_bounds__(256) void gemm_bf16(
    const u16* __restrict__ A, const u16* __restrict__ BT, void* __restrict__ Cout,
    const float* __restrict__ cosp, const float* __restrict__ sinp,
    int M, int N, int K, int mode)
{
    __shared__ u16 Al[128 * GBK];
    __shared__ u16 Bl[128 * GBK];
    const int tid = threadIdx.x;
    const int wid = tid >> 6, lane = tid & 63;
    const int m0 = blockIdx.y << 7, n0 = blockIdx.x << 7;
    const int wr = wid >> 1, wc = wid & 1;
    f32x4 acc[4][4] = {};

    const int srow = (wid << 5) + (lane >> 2);
    const int soff = (lane & 3) << 3;
    const u16* Ag0 = A + (size_t)(m0 + srow) * K + soff;
    const u16* Ag1 = A + (size_t)(m0 + srow + 16) * K + soff;
    const u16* Bg0 = BT + (size_t)(n0 + srow) * K + soff;
    const u16* Bg1 = BT + (size_t)(n0 + srow + 16) * K + soff;
    u16* Ald0 = &Al[(wid << 5) * GBK];
    u16* Ald1 = &Al[((wid << 5) + 16) * GBK];
    u16* Bld0 = &Bl[(wid << 5) * GBK];
    u16* Bld1 = &Bl[((wid << 5) + 16) * GBK];

    for (int k0 = 0; k0 < K; k0 += GBK) {
        __syncthreads();
        gl_lds16(Ag0 + k0, Ald0);
        gl_lds16(Ag1 + k0, Ald1);
        gl_lds16(Bg0 + k0, Bld0);
        gl_lds16(Bg1 + k0, Bld1);
        __syncthreads();
        bf16x8 af[4], bfr[4];
#pragma unroll
        for (int i = 0; i < 4; i++)
            af[i] = *(const bf16x8*)&Al[(((wr << 6) + (i << 4) + (lane & 15)) * GBK) + ((lane >> 4) << 3)];
#pragma unroll
        for (int i = 0; i < 4; i++)
            bfr[i] = *(const bf16x8*)&Bl[(((wc << 6) + (i << 4) + (lane & 15)) * GBK) + ((lane >> 4) << 3)];
#pragma unroll
        for (int mi = 0; mi < 4; mi++)
#pragma unroll
            for (int ni = 0; ni < 4; ni++)
                acc[mi][ni] = __builtin_amdgcn_mfma_f32_16x16x32_bf16(af[mi], bfr[ni], acc[mi][ni], 0, 0, 0);
    }

    const int colbase = n0 + (wc << 6) + (lane & 15);
    if (mode == 2) {
        float* C = (float*)Cout;
#pragma unroll
        for (int mi = 0; mi < 4; mi++)
#pragma unroll
            for (int r = 0; r < 4; r++) {
                int m = m0 + (wr << 6) + (mi << 4) + ((lane >> 4) << 2) + r;
                float* row = C + (size_t)m * N + colbase;
#pragma unroll
                for (int ni = 0; ni < 4; ni++) row[ni << 4] = acc[mi][ni][r];
            }
    } else if (mode == 1) {
        u16* C = (u16*)Cout;
#pragma unroll
        for (int mi = 0; mi < 4; mi++)
#pragma unroll
            for (int r = 0; r < 4; r++) {
                int m = m0 + (wr << 6) + (mi << 4) + ((lane >> 4) << 2) + r;
                const float* cb = cosp + ((size_t)m << 6);
                const float* sb = sinp + ((size_t)m << 6);
                u16* row = C + (size_t)m * N + colbase;
#pragma unroll
                for (int ni = 0; ni < 4; ni++) {
                    int d = (ni << 4) + (lane & 15);
                    float c = cb[d], s = sb[d];
                    float v0 = acc[mi][ni][r];
                    float vr = acc[mi][ni ^ 2][r];   // d +/- 32 partner
                    float o = fmaf(v0, c, (ni < 2 ? -vr : vr) * s);
                    row[ni << 4] = bf16u(o);
                }
            }
    } else {
        u16* C = (u16*)Cout;
#pragma unroll
        for (int mi = 0; mi < 4; mi++)
#pragma unroll
            for (int r = 0; r < 4; r++) {
                int m = m0 + (wr << 6) + (mi << 4) + ((lane >> 4) << 2) + r;
                u16* row = C + (size_t)m * N + colbase;
#pragma unroll
                for (int ni = 0; ni < 4; ni++) row[ni << 4] = bf16u(acc[mi][ni][r]);
            }
    }
}

// ---------------- axial attention, one (line, head) per block ----------------
// q/k/v: (16384 tokens x 1024) bf16, token = h*128+w. hmode 0: width attn (line=h),
// hmode 1: height attn (line=w). cat: (16384 x 2048) bf16.
__global__ __launch_bounds__(256) void axial_attn(
    const u16* __restrict__ q, const u16* __restrict__ k, const u16* __restrict__ v,
    const float* __restrict__ mask, u16* __restrict__ cat, int hmode)
{
    __shared__ u16 Kl[128 * 64];    // 16 KB, XOR-swizzled 16B chunks (^ row&7)
    __shared__ u16 VT[64 * 128];    // 16 KB, V^T, swizzled (^ d&15)
    __shared__ u16 Pl[128 * 128];   // 32 KB, P (q-major), swizzled (^ q&15)
    const int b = blockIdx.x;
    const int a = b >> 4, hd = b & 15;
    const int tid = threadIdx.x, wid = tid >> 6, lane = tid & 63;
    const int tmul = hmode ? 128 : 1;
    const int tadd = hmode ? a : (a << 7);
    const size_t hoff = (size_t)hd << 6;

    // ---- stage K via global_load_lds, swizzle applied on the SOURCE chunk ----
#pragma unroll
    for (int c = 0; c < 4; c++) {
        int row = (wid << 5) + (c << 3) + (lane >> 3);
        int sc = (lane & 7) ^ (row & 7);
        gl_lds16(k + (size_t)(row * tmul + tadd) * 1024 + hoff + (sc << 3),
                 &Kl[((wid << 5) + (c << 3)) << 6]);
    }
    // ---- stage V^T via registers (transpose), swizzled ----
#pragma unroll
    for (int i = 0; i < 4; i++) {
        int cid = tid + (i << 8);
        int j = cid >> 3;
        int d0 = (cid & 7) << 3;
        uint4 raw = *(const uint4*)(v + (size_t)(j * tmul + tadd) * 1024 + hoff + d0);
        const u16* e = (const u16*)&raw;
#pragma unroll
        for (int t = 0; t < 8; t++) {
            int d = d0 + t;
            VT[(d << 7) + (((j >> 3) ^ (d & 15)) << 3) + (j & 7)] = e[t];
        }
    }
    // ---- Q fragments straight from global ----
    bf16x8 aq[2][2];
#pragma unroll
    for (int qt = 0; qt < 2; qt++)
#pragma unroll
        for (int ks = 0; ks < 2; ks++) {
            int row = (wid << 5) + (qt << 4) + (lane & 15);
            aq[qt][ks] = *(const bf16x8*)(q + (size_t)(row * tmul + tadd) * 1024 + hoff
                                          + (ks << 5) + ((lane >> 4) << 3));
        }
    __syncthreads();

    // ---- S = Q K^T (wave handles 32 q-rows x all 128 keys) ----
    f32x4 S[2][8] = {};
#pragma unroll
    for (int kt = 0; kt < 8; kt++) {
        bf16x8 bk[2];
#pragma unroll
        for (int ks = 0; ks < 2; ks++) {
            int row = (kt << 4) + (lane & 15);
            int ch = ((ks << 2) + (lane >> 4)) ^ (row & 7);
            bk[ks] = *(const bf16x8*)&Kl[(row << 6) + (ch << 3)];
        }
#pragma unroll
        for (int qt = 0; qt < 2; qt++) {
            S[qt][kt] = __builtin_amdgcn_mfma_f32_16x16x32_bf16(aq[qt][0], bk[0], S[qt][kt], 0, 0, 0);
            S[qt][kt] = __builtin_amdgcn_mfma_f32_16x16x32_bf16(aq[qt][1], bk[1], S[qt][kt], 0, 0, 0);
        }
    }

    // ---- softmax (full row in-register; 16-lane shfl_xor reduce) ----
    const float scale = 0.03125f;   // 1/sqrt(1024)
#pragma unroll
    for (int qt = 0; qt < 2; qt++) {
#pragma unroll
        for (int r = 0; r < 4; r++) {
            int qrow = (wid << 5) + (qt << 4) + ((lane >> 4) << 2) + r;
            const float* mrow = mask + (hmode ? (a << 7) : (qrow << 7));
            float mx = -1e30f;
#pragma unroll
            for (int kt = 0; kt < 8; kt++) {
                float sv = fmaf(S[qt][kt][r], scale, mrow[(kt << 4) + (lane & 15)]);
                S[qt][kt][r] = sv;
                mx = fmaxf(mx, sv);
            }
            mx = fmaxf(mx, __shfl_xor(mx, 1));
            mx = fmaxf(mx, __shfl_xor(mx, 2));
            mx = fmaxf(mx, __shfl_xor(mx, 4));
            mx = fmaxf(mx, __shfl_xor(mx, 8));
            float sum = 0.f;
#pragma unroll
            for (int kt = 0; kt < 8; kt++) {
                float p = __expf(S[qt][kt][r] - mx);
                S[qt][kt][r] = p;
                sum += p;
            }
            sum += __shfl_xor(sum, 1);
            sum += __shfl_xor(sum, 2);
            sum += __shfl_xor(sum, 4);
            sum += __shfl_xor(sum, 8);
            float rinv = 1.0f / sum;
#pragma unroll
            for (int kt = 0; kt < 8; kt++) {
                int kcol = (kt << 4) + (lane & 15);
                int ch = (kcol >> 3) ^ (qrow & 15);
                Pl[(qrow << 7) + (ch << 3) + (kcol & 7)] = bf16u(S[qt][kt][r] * rinv);
            }
        }
    }
    __syncthreads();

    // ---- O^T = V^T * P^T  (A = V^T rows d, B cols = this wave's q rows) ----
    f32x4 O[4][2] = {};
#pragma unroll
    for (int ks = 0; ks < 4; ks++) {
        bf16x8 av[4], bp[2];
#pragma unroll
        for (int dt = 0; dt < 4; dt++) {
            int drow = (dt << 4) + (lane & 15);
            int ch = ((ks << 2) + (lane >> 4)) ^ (drow & 15);
            av[dt] = *(const bf16x8*)&VT[(drow << 7) + (ch << 3)];
        }
#pragma unroll
        for (int qt = 0; qt < 2; qt++) {
            int qrow = (wid << 5) + (qt << 4) + (lane & 15);
            int ch = ((ks << 2) + (lane >> 4)) ^ (qrow & 15);
            bp[qt] = *(const bf16x8*)&Pl[(qrow << 7) + (ch << 3)];
        }
#pragma unroll
        for (int dt = 0; dt < 4; dt++)
#pragma unroll
            for (int qt = 0; qt < 2; qt++)
                O[dt][qt] = __builtin_amdgcn_mfma_f32_16x16x32_bf16(av[dt], bp[qt], O[dt][qt], 0, 0, 0);
    }

    // ---- write cat (bf16), packed 4-wide along d ----
    const int cbase = (hmode ? 1024 : 0) + (hd << 6);
#pragma unroll
    for (int dt = 0; dt < 4; dt++)
#pragma unroll
        for (int qt = 0; qt < 2; qt++) {
            int qrow = (wid << 5) + (qt << 4) + (lane & 15);
            int d0 = (dt << 4) + ((lane >> 4) << 2);
            size_t base = ((size_t)(qrow * tmul + tadd) << 11) + cbase + d0;
            ushort4 pk;
            pk.x = bf16u(O[dt][qt][0]);
            pk.y = bf16u(O[dt][qt][1]);
            pk.z = bf16u(O[dt][qt][2]);
            pk.w = bf16u(O[dt][qt][3]);
            *(ushort4*)(cat + base) = pk;
        }
}

extern "C" void kernel_launch(void* const* d_in, const int* in_sizes, int n_in,
                              void* d_out, int out_size, void* d_ws, size_t ws_size,
                              hipStream_t stream)
{
    (void)in_sizes; (void)n_in; (void)out_size; (void)ws_size;
    const float* hidden = (const float*)d_in[0];
    const float* mask   = (const float*)d_in[1];
    const float* cosp   = (const float*)d_in[2];
    const float* sinp   = (const float*)d_in[3];
    const float* Wq     = (const float*)d_in[4];
    const float* Wk     = (const float*)d_in[5];
    const float* Wv     = (const float*)d_in[6];
    const float* Wo     = (const float*)d_in[7];

    char* ws = (char*)d_ws;
    // Layout (cat reuses the region of Xb + WqT/WkT/WvT, which are dead by then):
    u16* Xb  = (u16*)(ws);                    // 33,554,432 B
    u16* WqT = (u16*)(ws + 33554432);         //  2,097,152 B
    u16* WkT = (u16*)(ws + 35651584);
    u16* WvT = (u16*)(ws + 37748736);
    u16* cat = (u16*)(ws);                    // 67,108,864 B (overlap, stream-ordered safe)
    u16* WoT = (u16*)(ws + 67108864);         //  4,194,304 B
    u16* qb  = (u16*)(ws + 71303168);         // 33,554,432 B
    u16* kb  = (u16*)(ws + 104857600);
    u16* vb  = (u16*)(ws + 138412032);        // end = 171,966,464 B

    cvt_x_kernel<<<16384, 256, 0, stream>>>((const float4*)hidden, (ushort4*)Xb, 4194304);

    transp_kernel<<<dim3(32, 32), 256, 0, stream>>>(Wq, WqT, 1024, 1024);
    transp_kernel<<<dim3(32, 32), 256, 0, stream>>>(Wk, WkT, 1024, 1024);
    transp_kernel<<<dim3(32, 32), 256, 0, stream>>>(Wv, WvT, 1024, 1024);
    transp_kernel<<<dim3(32, 64), 256, 0, stream>>>(Wo, WoT, 2048, 1024);

    gemm_bf16<<<dim3(8, 128), 256, 0, stream>>>(Xb, WqT, qb, cosp, sinp, 16384, 1024, 1024, 1);
    gemm_bf16<<<dim3(8, 128), 256, 0, stream>>>(Xb, WkT, kb, cosp, sinp, 16384, 1024, 1024, 1);
    gemm_bf16<<<dim3(8, 128), 256, 0, stream>>>(Xb, WvT, vb, cosp, sinp, 16384, 1024, 1024, 0);

    axial_attn<<<2048, 256, 0, stream>>>(qb, kb, vb, mask, cat, 0);
    axial_attn<<<2048, 256, 0, stream>>>(qb, kb, vb, mask, cat, 1);

    gemm_bf16<<<dim3(8, 128), 256, 0, stream>>>(cat, WoT, d_out, nullptr, nullptr, 16384, 1024, 2048, 2);
}

// Round 2
// 366.148 us; speedup vs baseline: 1.2101x; 1.2101x over previous
//
#include <hip/hip_runtime.h>

typedef unsigned short u16;
typedef unsigned int   u32;
typedef __bf16 bf16;
typedef bf16  bf16x8 __attribute__((ext_vector_type(8)));
typedef float f32x4  __attribute__((ext_vector_type(4)));

__device__ __forceinline__ u16 bf16u(float f) {
    u32 x = __builtin_bit_cast(u32, f);
    x += 0x7fffu + ((x >> 16) & 1u);   // RNE
    return (u16)(x >> 16);
}

__device__ __forceinline__ void gl_lds16(const void* g, void* l) {
    __builtin_amdgcn_global_load_lds(
        (const __attribute__((address_space(1))) u32*)g,
        (__attribute__((address_space(3))) u32*)l, 16, 0, 0);
}

// ---------------- fp32 -> bf16 convert (vectorized) ----------------
__global__ __launch_bounds__(256) void cvt_x_kernel(const float4* __restrict__ in,
                                                    ushort4* __restrict__ out, int n4) {
    int i = blockIdx.x * 256 + threadIdx.x;
    if (i >= n4) return;
    float4 f = in[i];
    ushort4 o;
    o.x = bf16u(f.x); o.y = bf16u(f.y); o.z = bf16u(f.z); o.w = bf16u(f.w);
    out[i] = o;
}

// ---------------- fp32 W[rows][cols] -> bf16 W^T[cols][rows] ----------------
__global__ __launch_bounds__(256) void transp_kernel(const float* __restrict__ W,
                                                     u16* __restrict__ WT,
                                                     int rows, int cols) {
    __shared__ float t[32][33];
    int bx = blockIdx.x * 32, by = blockIdx.y * 32;
    int x = threadIdx.x & 31, y = threadIdx.x >> 5;   // y in 0..7
#pragma unroll
    for (int i = 0; i < 32; i += 8)
        t[y + i][x] = W[(size_t)(by + y + i) * cols + bx + x];
    __syncthreads();
#pragma unroll
    for (int i = 0; i < 32; i += 8)
        WT[(size_t)(bx + y + i) * rows + by + x] = bf16u(t[x][y + i]);
}

// ---------------- bf16 GEMM: C[M][N] = A[M][K] * BT[N][K]^T ----------------
// 2-phase double-buffered LDS (T3-min), XCD-chunk swizzle (T1/m204).
// mode 1: bf16 out, fused RoPE when global col < 2048 (fused QKV).
// mode 2: fp32 out.
#define GBK 32
__global__ __launch_bounds__(256) void gemm2(
    const u16* __restrict__ A, const u16* __restrict__ BT, void* __restrict__ Cout,
    const float* __restrict__ cosp, const float* __restrict__ sinp,
    int M, int N, int K, int mode)
{
    __shared__ u16 Al[2][128 * GBK];
    __shared__ u16 Bl[2][128 * GBK];
    const int tid = threadIdx.x;
    const int wid = tid >> 6, lane = tid & 63;
    // ---- XCD-chunk swizzle: same-m-panel blocks land on one XCD ----
    const int nx = gridDim.x;
    const int nwg = nx * gridDim.y;            // always % 8 == 0 here
    const int orig = blockIdx.y * nx + blockIdx.x;
    const int vid = (orig & 7) * (nwg >> 3) + (orig >> 3);
    const int m0 = (vid / nx) << 7, n0 = (vid % nx) << 7;
    const int wr = wid >> 1, wc = wid & 1;
    f32x4 acc[4][4] = {};

    const int srow = (wid << 5) + (lane >> 2);
    const int soff = (lane & 3) << 3;
    const u16* Ag0 = A + (size_t)(m0 + srow) * K + soff;
    const u16* Ag1 = Ag0 + (size_t)16 * K;
    const u16* Bg0 = BT + (size_t)(n0 + srow) * K + soff;
    const u16* Bg1 = Bg0 + (size_t)16 * K;
    const int l0 = (wid << 5) * GBK;
    const int l1 = ((wid << 5) + 16) * GBK;

    const int nt = K >> 5;
    // prologue: stage tile 0 into buffer 0
    gl_lds16(Ag0, &Al[0][l0]);
    gl_lds16(Ag1, &Al[0][l1]);
    gl_lds16(Bg0, &Bl[0][l0]);
    gl_lds16(Bg1, &Bl[0][l1]);
    __syncthreads();

    int cur = 0;
    for (int t = 0; t < nt; ++t) {
        if (t + 1 < nt) {                     // issue next-tile loads FIRST
            const int k0 = (t + 1) << 5;
            const int nb = cur ^ 1;
            gl_lds16(Ag0 + k0, &Al[nb][l0]);
            gl_lds16(Ag1 + k0, &Al[nb][l1]);
            gl_lds16(Bg0 + k0, &Bl[nb][l0]);
            gl_lds16(Bg1 + k0, &Bl[nb][l1]);
        }
        bf16x8 af[4], bfr[4];
#pragma unroll
        for (int i = 0; i < 4; i++)
            af[i] = *(const bf16x8*)&Al[cur][(((wr << 6) + (i << 4) + (lane & 15)) * GBK) + ((lane >> 4) << 3)];
#pragma unroll
        for (int i = 0; i < 4; i++)
            bfr[i] = *(const bf16x8*)&Bl[cur][(((wc << 6) + (i << 4) + (lane & 15)) * GBK) + ((lane >> 4) << 3)];
#pragma unroll
        for (int mi = 0; mi < 4; mi++)
#pragma unroll
            for (int ni = 0; ni < 4; ni++)
                acc[mi][ni] = __builtin_amdgcn_mfma_f32_16x16x32_bf16(af[mi], bfr[ni], acc[mi][ni], 0, 0, 0);
        __syncthreads();                      // drains vmcnt(0): next buffer ready
        cur ^= 1;
    }

    const int colbase = n0 + (wc << 6) + (lane & 15);
    if (mode == 2) {
        float* C = (float*)Cout;
#pragma unroll
        for (int mi = 0; mi < 4; mi++)
#pragma unroll
            for (int r = 0; r < 4; r++) {
                int m = m0 + (wr << 6) + (mi << 4) + ((lane >> 4) << 2) + r;
                float* row = C + (size_t)m * N + colbase;
#pragma unroll
                for (int ni = 0; ni < 4; ni++) row[ni << 4] = acc[mi][ni][r];
            }
    } else if (n0 < 2048) {                   // fused QKV: RoPE region (Q and K)
        u16* C = (u16*)Cout;
#pragma unroll
        for (int mi = 0; mi < 4; mi++)
#pragma unroll
            for (int r = 0; r < 4; r++) {
                int m = m0 + (wr << 6) + (mi << 4) + ((lane >> 4) << 2) + r;
                const float* cb = cosp + ((size_t)m << 6);
                const float* sb = sinp + ((size_t)m << 6);
                u16* row = C + (size_t)m * N + colbase;
#pragma unroll
                for (int ni = 0; ni < 4; ni++) {
                    int d = (ni << 4) + (lane & 15);   // head-dim position (0..63)
                    float c = cb[d], s = sb[d];
                    float v0 = acc[mi][ni][r];
                    float vr = acc[mi][ni ^ 2][r];     // d +/- 32 partner
                    float o = fmaf(v0, c, (ni < 2 ? -vr : vr) * s);
                    row[ni << 4] = bf16u(o);
                }
            }
    } else {                                  // V region: plain bf16
        u16* C = (u16*)Cout;
#pragma unroll
        for (int mi = 0; mi < 4; mi++)
#pragma unroll
            for (int r = 0; r < 4; r++) {
                int m = m0 + (wr << 6) + (mi << 4) + ((lane >> 4) << 2) + r;
                u16* row = C + (size_t)m * N + colbase;
#pragma unroll
                for (int ni = 0; ni < 4; ni++) row[ni << 4] = bf16u(acc[mi][ni][r]);
            }
    }
}

// ---------------- axial attention, one (line, head) per block ----------------
// qkv: (16384 tokens x 3072) bf16, cols [0,1024)=q [1024,2048)=k [2048,3072)=v.
// token = h*128+w. hmode 0: width attn (line=h), hmode 1: height attn (line=w).
// cat: (16384 x 2048) bf16.
__global__ __launch_bounds__(256) void axial_attn(
    const u16* __restrict__ qkv, const float* __restrict__ mask,
    u16* __restrict__ cat, int hmode)
{
    __shared__ u16 Kl[128 * 64];    // 16 KB, XOR-swizzled 16B chunks (^ row&7)
    __shared__ u16 VT[64 * 128];    // 16 KB, V^T, swizzled (^ d&15)
    __shared__ u16 Pl[128 * 128];   // 32 KB, P (q-major), swizzled (^ q&15)
    // XCD-chunk swizzle: 16 heads of the same line share k/v rows -> same XCD
    const int orig = blockIdx.x;
    const int b = (orig & 7) * 256 + (orig >> 3);   // nwg = 2048
    const int a = b >> 4, hd = b & 15;
    const int tid = threadIdx.x, wid = tid >> 6, lane = tid & 63;
    const int tmul = hmode ? 128 : 1;
    const int tadd = hmode ? a : (a << 7);
    const size_t hoff = (size_t)hd << 6;

    // ---- stage K via global_load_lds, swizzle applied on the SOURCE chunk ----
#pragma unroll
    for (int c = 0; c < 4; c++) {
        int row = (wid << 5) + (c << 3) + (lane >> 3);
        int sc = (lane & 7) ^ (row & 7);
        gl_lds16(qkv + (size_t)(row * tmul + tadd) * 3072 + 1024 + hoff + (sc << 3),
                 &Kl[((wid << 5) + (c << 3)) << 6]);
    }
    // ---- stage V^T via registers (transpose), swizzled ----
#pragma unroll
    for (int i = 0; i < 4; i++) {
        int cid = tid + (i << 8);
        int j = cid >> 3;
        int d0 = (cid & 7) << 3;
        uint4 raw = *(const uint4*)(qkv + (size_t)(j * tmul + tadd) * 3072 + 2048 + hoff + d0);
        const u16* e = (const u16*)&raw;
#pragma unroll
        for (int t = 0; t < 8; t++) {
            int d = d0 + t;
            VT[(d << 7) + (((j >> 3) ^ (d & 15)) << 3) + (j & 7)] = e[t];
        }
    }
    // ---- Q fragments straight from global ----
    bf16x8 aq[2][2];
#pragma unroll
    for (int qt = 0; qt < 2; qt++)
#pragma unroll
        for (int ks = 0; ks < 2; ks++) {
            int row = (wid << 5) + (qt << 4) + (lane & 15);
            aq[qt][ks] = *(const bf16x8*)(qkv + (size_t)(row * tmul + tadd) * 3072 + hoff
                                          + (ks << 5) + ((lane >> 4) << 3));
        }
    __syncthreads();

    // ---- S = Q K^T (wave handles 32 q-rows x all 128 keys) ----
    f32x4 S[2][8] = {};
#pragma unroll
    for (int kt = 0; kt < 8; kt++) {
        bf16x8 bk[2];
#pragma unroll
        for (int ks = 0; ks < 2; ks++) {
            int row = (kt << 4) + (lane & 15);
            int ch = ((ks << 2) + (lane >> 4)) ^ (row & 7);
            bk[ks] = *(const bf16x8*)&Kl[(row << 6) + (ch << 3)];
        }
#pragma unroll
        for (int qt = 0; qt < 2; qt++) {
            S[qt][kt] = __builtin_amdgcn_mfma_f32_16x16x32_bf16(aq[qt][0], bk[0], S[qt][kt], 0, 0, 0);
            S[qt][kt] = __builtin_amdgcn_mfma_f32_16x16x32_bf16(aq[qt][1], bk[1], S[qt][kt], 0, 0, 0);
        }
    }

    // ---- softmax (full row in-register; 16-lane shfl_xor reduce) ----
    const float scale = 0.03125f;   // 1/sqrt(1024)
#pragma unroll
    for (int qt = 0; qt < 2; qt++) {
#pragma unroll
        for (int r = 0; r < 4; r++) {
            int qrow = (wid << 5) + (qt << 4) + ((lane >> 4) << 2) + r;
            const float* mrow = mask + (hmode ? (a << 7) : (qrow << 7));
            float mx = -1e30f;
#pragma unroll
            for (int kt = 0; kt < 8; kt++) {
                float sv = fmaf(S[qt][kt][r], scale, mrow[(kt << 4) + (lane & 15)]);
                S[qt][kt][r] = sv;
                mx = fmaxf(mx, sv);
            }
            mx = fmaxf(mx, __shfl_xor(mx, 1));
            mx = fmaxf(mx, __shfl_xor(mx, 2));
            mx = fmaxf(mx, __shfl_xor(mx, 4));
            mx = fmaxf(mx, __shfl_xor(mx, 8));
            float sum = 0.f;
#pragma unroll
            for (int kt = 0; kt < 8; kt++) {
                float p = __expf(S[qt][kt][r] - mx);
                S[qt][kt][r] = p;
                sum += p;
            }
            sum += __shfl_xor(sum, 1);
            sum += __shfl_xor(sum, 2);
            sum += __shfl_xor(sum, 4);
            sum += __shfl_xor(sum, 8);
            float rinv = 1.0f / sum;
#pragma unroll
            for (int kt = 0; kt < 8; kt++) {
                int kcol = (kt << 4) + (lane & 15);
                int ch = (kcol >> 3) ^ (qrow & 15);
                Pl[(qrow << 7) + (ch << 3) + (kcol & 7)] = bf16u(S[qt][kt][r] * rinv);
            }
        }
    }
    __syncthreads();

    // ---- O^T = V^T * P^T  (A = V^T rows d, B cols = this wave's q rows) ----
    f32x4 O[4][2] = {};
#pragma unroll
    for (int ks = 0; ks < 4; ks++) {
        bf16x8 av[4], bp[2];
#pragma unroll
        for (int dt = 0; dt < 4; dt++) {
            int drow = (dt << 4) + (lane & 15);
            int ch = ((ks << 2) + (lane >> 4)) ^ (drow & 15);
            av[dt] = *(const bf16x8*)&VT[(drow << 7) + (ch << 3)];
        }
#pragma unroll
        for (int qt = 0; qt < 2; qt++) {
            int qrow = (wid << 5) + (qt << 4) + (lane & 15);
            int ch = ((ks << 2) + (lane >> 4)) ^ (qrow & 15);
            bp[qt] = *(const bf16x8*)&Pl[(qrow << 7) + (ch << 3)];
        }
#pragma unroll
        for (int dt = 0; dt < 4; dt++)
#pragma unroll
            for (int qt = 0; qt < 2; qt++)
                O[dt][qt] = __builtin_amdgcn_mfma_f32_16x16x32_bf16(av[dt], bp[qt], O[dt][qt], 0, 0, 0);
    }

    // ---- write cat (bf16), packed 4-wide along d ----
    const int cbase = (hmode ? 1024 : 0) + (hd << 6);
#pragma unroll
    for (int dt = 0; dt < 4; dt++)
#pragma unroll
        for (int qt = 0; qt < 2; qt++) {
            int qrow = (wid << 5) + (qt << 4) + (lane & 15);
            int d0 = (dt << 4) + ((lane >> 4) << 2);
            size_t base = ((size_t)(qrow * tmul + tadd) << 11) + cbase + d0;
            ushort4 pk;
            pk.x = bf16u(O[dt][qt][0]);
            pk.y = bf16u(O[dt][qt][1]);
            pk.z = bf16u(O[dt][qt][2]);
            pk.w = bf16u(O[dt][qt][3]);
            *(ushort4*)(cat + base) = pk;
        }
}

extern "C" void kernel_launch(void* const* d_in, const int* in_sizes, int n_in,
                              void* d_out, int out_size, void* d_ws, size_t ws_size,
                              hipStream_t stream)
{
    (void)in_sizes; (void)n_in; (void)out_size; (void)ws_size;
    const float* hidden = (const float*)d_in[0];
    const float* mask   = (const float*)d_in[1];
    const float* cosp   = (const float*)d_in[2];
    const float* sinp   = (const float*)d_in[3];
    const float* Wq     = (const float*)d_in[4];
    const float* Wk     = (const float*)d_in[5];
    const float* Wv     = (const float*)d_in[6];
    const float* Wo     = (const float*)d_in[7];

    char* ws = (char*)d_ws;
    // Layout (stream-ordered reuse: cat overlaps Xb+WqkvT, which die after QKV GEMM):
    u16* Xb    = (u16*)(ws);                  // 33,554,432 B
    u16* WqkvT = (u16*)(ws + 33554432);       //  6,291,456 B  (ends 39,845,888)
    u16* cat   = (u16*)(ws);                  // 67,108,864 B  (overlap, safe)
    u16* WoT   = (u16*)(ws + 67108864);       //  4,194,304 B  (ends 71,303,168)
    u16* qkvb  = (u16*)(ws + 71303168);       // 100,663,296 B (ends 171,966,464)

    cvt_x_kernel<<<16384, 256, 0, stream>>>((const float4*)hidden, (ushort4*)Xb, 4194304);

    transp_kernel<<<dim3(32, 32), 256, 0, stream>>>(Wq, WqkvT,               1024, 1024);
    transp_kernel<<<dim3(32, 32), 256, 0, stream>>>(Wk, WqkvT + 1024 * 1024, 1024, 1024);
    transp_kernel<<<dim3(32, 32), 256, 0, stream>>>(Wv, WqkvT + 2048 * 1024, 1024, 1024);
    transp_kernel<<<dim3(32, 64), 256, 0, stream>>>(Wo, WoT, 2048, 1024);

    // fused QKV projection + RoPE: [16384,1024] x [1024,3072] -> [16384,3072]
    gemm2<<<dim3(24, 128), 256, 0, stream>>>(Xb, WqkvT, qkvb, cosp, sinp, 16384, 3072, 1024, 1);

    axial_attn<<<2048, 256, 0, stream>>>(qkvb, mask, cat, 0);
    axial_attn<<<2048, 256, 0, stream>>>(qkvb, mask, cat, 1);

    // output projection: [16384,2048] x [2048,1024] -> fp32 [16384,1024]
    gemm2<<<dim3(8, 128), 256, 0, stream>>>(cat, WoT, d_out, nullptr, nullptr, 16384, 1024, 2048, 2);
}

// Round 3
// 362.037 us; speedup vs baseline: 1.2238x; 1.0114x over previous
//
#include <hip/hip_runtime.h>

typedef unsigned short u16;
typedef unsigned int   u32;
typedef __bf16 bf16;
typedef bf16  bf16x8 __attribute__((ext_vector_type(8)));
typedef float f32x4  __attribute__((ext_vector_type(4)));

__device__ __forceinline__ u16 bf16u(float f) {
    u32 x = __builtin_bit_cast(u32, f);
    x += 0x7fffu + ((x >> 16) & 1u);   // RNE
    return (u16)(x >> 16);
}

__device__ __forceinline__ void gl_lds16(const void* g, void* l) {
    __builtin_amdgcn_global_load_lds(
        (const __attribute__((address_space(1))) u32*)g,
        (__attribute__((address_space(3))) u32*)l, 16, 0, 0);
}

// ---------------- fp32 -> bf16 convert (vectorized) ----------------
__global__ __launch_bounds__(256) void cvt_x_kernel(const float4* __restrict__ in,
                                                    ushort4* __restrict__ out, int n4) {
    int i = blockIdx.x * 256 + threadIdx.x;
    if (i >= n4) return;
    float4 f = in[i];
    ushort4 o;
    o.x = bf16u(f.x); o.y = bf16u(f.y); o.z = bf16u(f.z); o.w = bf16u(f.w);
    out[i] = o;
}

// ---------------- fp32 W[rows][cols] -> bf16 W^T[cols][rows] ----------------
__global__ __launch_bounds__(256) void transp_kernel(const float* __restrict__ W,
                                                     u16* __restrict__ WT,
                                                     int rows, int cols) {
    __shared__ float t[32][33];
    int bx = blockIdx.x * 32, by = blockIdx.y * 32;
    int x = threadIdx.x & 31, y = threadIdx.x >> 5;
#pragma unroll
    for (int i = 0; i < 32; i += 8)
        t[y + i][x] = W[(size_t)(by + y + i) * cols + bx + x];
    __syncthreads();
#pragma unroll
    for (int i = 0; i < 32; i += 8)
        WT[(size_t)(bx + y + i) * rows + by + x] = bf16u(t[x][y + i]);
}

// ============ 256x256-tile GEMM, 4-deep pipelined LDS, counted vmcnt ========
// C[M][N] = A[M][K] * BT[N][K]^T.  512 threads = 8 waves (2m x 4n),
// wave tile 128x64. K-step 32. LDS: 4 buffers x (A 16KB + B 16KB) = 128 KB.
// Schedule per K-tile t:
//   lgkmcnt(0)            -- my frag reads of tile t-1 drained (buffer reuse safe)
//   vmcnt(counted)        -- my stage(t) landed; stages t+1,t+2 stay in flight
//   s_barrier             -- all waves: tile t ready, tile t-1 reads done
//   issue stage(t+3) -> buf[(t+3)&3]   (buffer last read at iter t-1: safe)
//   ds_read 12 frags (chunk-XOR swizzled) ; 32 MFMA (setprio-wrapped)
// mode 1: bf16 out, fused RoPE when col < 2048.   mode 2: fp32 out.
#define BK2 32
__global__ __launch_bounds__(512, 2) void gemm8(
    const u16* __restrict__ A, const u16* __restrict__ BT, void* __restrict__ Cout,
    const float* __restrict__ cosp, const float* __restrict__ sinp,
    int M, int N, int K, int mode)
{
    __shared__ u16 Al[4][256 * BK2];   // 64 KB
    __shared__ u16 Bl[4][256 * BK2];   // 64 KB
    const int tid = threadIdx.x;
    const int wid = tid >> 6, lane = tid & 63;
    // XCD-chunk swizzle (nwg % 8 == 0 for all our grids)
    const int nx = gridDim.x;
    const int nwg = nx * gridDim.y;
    const int orig = blockIdx.y * nx + blockIdx.x;
    const int vid = (orig & 7) * (nwg >> 3) + (orig >> 3);
    const int m0 = (vid / nx) << 8, n0 = (vid % nx) << 8;
    const int wr = wid >> 2, wc = wid & 3;

    // ---- staging descriptors: 2 A-loads + 2 B-loads per thread per K-tile ----
    // linear LDS chunk c = l*512 + tid; row r = c>>2; physical chunk c&3 holds
    // logical chunk (c&3) ^ ((r>>1)&3)  -> fetch that chunk from global.
    const int c0 = tid, c1 = 512 + tid;
    const int r0 = c0 >> 2, r1 = c1 >> 2;
    const int ch0 = (c0 & 3) ^ ((r0 >> 1) & 3);
    const int ch1 = (c1 & 3) ^ ((r1 >> 1) & 3);
    const u16* aS0 = A + (size_t)(m0 + r0) * K + (ch0 << 3);
    const u16* aS1 = A + (size_t)(m0 + r1) * K + (ch1 << 3);
    const u16* bS0 = BT + (size_t)(n0 + r0) * K + (ch0 << 3);
    const u16* bS1 = BT + (size_t)(n0 + r1) * K + (ch1 << 3);
    const int ldsw = wid << 9;   // wave-uniform dest (u16 idx); HW adds lane*16B

#define STAGE(tt) do { int _b = (tt) & 3; size_t _ko = (size_t)(tt) * BK2; \
        gl_lds16(aS0 + _ko, &Al[_b][ldsw]);         \
        gl_lds16(aS1 + _ko, &Al[_b][4096 + ldsw]);  \
        gl_lds16(bS0 + _ko, &Bl[_b][ldsw]);         \
        gl_lds16(bS1 + _ko, &Bl[_b][4096 + ldsw]);  } while (0)

    const int nt = K >> 5;
    STAGE(0); STAGE(1); STAGE(2);

    // frag-read swizzle is lane-constant: physical chunk = (lane>>4) ^ ((lane>>1)&3)
    const int ch_rd = (((lane >> 4) ^ ((lane >> 1) & 3)) << 3);
    const int ra = (wr << 7) + (lane & 15);   // A row base for this lane
    const int rb = (wc << 6) + (lane & 15);   // B row base for this lane

    f32x4 acc[8][4] = {};

    for (int t = 0; t < nt; ++t) {
        asm volatile("s_waitcnt lgkmcnt(0)" ::: "memory");
        if (t + 2 < nt)      asm volatile("s_waitcnt vmcnt(8)" ::: "memory");
        else if (t + 1 < nt) asm volatile("s_waitcnt vmcnt(4)" ::: "memory");
        else                 asm volatile("s_waitcnt vmcnt(0)" ::: "memory");
        __builtin_amdgcn_s_barrier();
        if (t + 3 < nt) STAGE(t + 3);

        const u16* Ab = &Al[t & 3][0];
        const u16* Bb = &Bl[t & 3][0];
        bf16x8 af[8], bfr[4];
#pragma unroll
        for (int mi = 0; mi < 8; mi++)
            af[mi] = *(const bf16x8*)&Ab[((ra + (mi << 4)) << 5) + ch_rd];
#pragma unroll
        for (int ni = 0; ni < 4; ni++)
            bfr[ni] = *(const bf16x8*)&Bb[((rb + (ni << 4)) << 5) + ch_rd];

        __builtin_amdgcn_s_setprio(1);
#pragma unroll
        for (int mi = 0; mi < 8; mi++)
#pragma unroll
            for (int ni = 0; ni < 4; ni++)
                acc[mi][ni] = __builtin_amdgcn_mfma_f32_16x16x32_bf16(af[mi], bfr[ni], acc[mi][ni], 0, 0, 0);
        __builtin_amdgcn_s_setprio(0);
    }
#undef STAGE

    const int colbase = n0 + (wc << 6) + (lane & 15);
    if (mode == 2) {
        float* C = (float*)Cout;
#pragma unroll
        for (int mi = 0; mi < 8; mi++)
#pragma unroll
            for (int r = 0; r < 4; r++) {
                int m = m0 + (wr << 7) + (mi << 4) + ((lane >> 4) << 2) + r;
                float* row = C + (size_t)m * N + colbase;
#pragma unroll
                for (int ni = 0; ni < 4; ni++) row[ni << 4] = acc[mi][ni][r];
            }
    } else if (n0 < 2048) {                   // fused QKV: RoPE region (Q and K)
        u16* C = (u16*)Cout;
#pragma unroll
        for (int mi = 0; mi < 8; mi++)
#pragma unroll
            for (int r = 0; r < 4; r++) {
                int m = m0 + (wr << 7) + (mi << 4) + ((lane >> 4) << 2) + r;
                const float* cb = cosp + ((size_t)m << 6);
                const float* sb = sinp + ((size_t)m << 6);
                u16* row = C + (size_t)m * N + colbase;
#pragma unroll
                for (int ni = 0; ni < 4; ni++) {
                    int d = (ni << 4) + (lane & 15);   // head-dim pos (0..63)
                    float c = cb[d], s = sb[d];
                    float v0 = acc[mi][ni][r];
                    float vr = acc[mi][ni ^ 2][r];     // d +/- 32 partner
                    float o = fmaf(v0, c, (ni < 2 ? -vr : vr) * s);
                    row[ni << 4] = bf16u(o);
                }
            }
    } else {                                  // V region: plain bf16
        u16* C = (u16*)Cout;
#pragma unroll
        for (int mi = 0; mi < 8; mi++)
#pragma unroll
            for (int r = 0; r < 4; r++) {
                int m = m0 + (wr << 7) + (mi << 4) + ((lane >> 4) << 2) + r;
                u16* row = C + (size_t)m * N + colbase;
#pragma unroll
                for (int ni = 0; ni < 4; ni++) row[ni << 4] = bf16u(acc[mi][ni][r]);
            }
    }
}

// ---------------- axial attention, one (line, head) per block ----------------
__global__ __launch_bounds__(256) void axial_attn(
    const u16* __restrict__ qkv, const float* __restrict__ mask,
    u16* __restrict__ cat, int hmode)
{
    __shared__ u16 Kl[128 * 64];    // XOR-swizzled 16B chunks (^ row&7)
    __shared__ u16 VT[64 * 128];    // V^T, swizzled (^ d&15)
    __shared__ u16 Pl[128 * 128];   // P (q-major), swizzled (^ q&15)
    const int orig = blockIdx.x;
    const int b = (orig & 7) * 256 + (orig >> 3);   // nwg = 2048
    const int a = b >> 4, hd = b & 15;
    const int tid = threadIdx.x, wid = tid >> 6, lane = tid & 63;
    const int tmul = hmode ? 128 : 1;
    const int tadd = hmode ? a : (a << 7);
    const size_t hoff = (size_t)hd << 6;

#pragma unroll
    for (int c = 0; c < 4; c++) {
        int row = (wid << 5) + (c << 3) + (lane >> 3);
        int sc = (lane & 7) ^ (row & 7);
        gl_lds16(qkv + (size_t)(row * tmul + tadd) * 3072 + 1024 + hoff + (sc << 3),
                 &Kl[((wid << 5) + (c << 3)) << 6]);
    }
#pragma unroll
    for (int i = 0; i < 4; i++) {
        int cid = tid + (i << 8);
        int j = cid >> 3;
        int d0 = (cid & 7) << 3;
        uint4 raw = *(const uint4*)(qkv + (size_t)(j * tmul + tadd) * 3072 + 2048 + hoff + d0);
        const u16* e = (const u16*)&raw;
#pragma unroll
        for (int t = 0; t < 8; t++) {
            int d = d0 + t;
            VT[(d << 7) + (((j >> 3) ^ (d & 15)) << 3) + (j & 7)] = e[t];
        }
    }
    bf16x8 aq[2][2];
#pragma unroll
    for (int qt = 0; qt < 2; qt++)
#pragma unroll
        for (int ks = 0; ks < 2; ks++) {
            int row = (wid << 5) + (qt << 4) + (lane & 15);
            aq[qt][ks] = *(const bf16x8*)(qkv + (size_t)(row * tmul + tadd) * 3072 + hoff
                                          + (ks << 5) + ((lane >> 4) << 3));
        }
    __syncthreads();

    f32x4 S[2][8] = {};
#pragma unroll
    for (int kt = 0; kt < 8; kt++) {
        bf16x8 bk[2];
#pragma unroll
        for (int ks = 0; ks < 2; ks++) {
            int row = (kt << 4) + (lane & 15);
            int ch = ((ks << 2) + (lane >> 4)) ^ (row & 7);
            bk[ks] = *(const bf16x8*)&Kl[(row << 6) + (ch << 3)];
        }
#pragma unroll
        for (int qt = 0; qt < 2; qt++) {
            S[qt][kt] = __builtin_amdgcn_mfma_f32_16x16x32_bf16(aq[qt][0], bk[0], S[qt][kt], 0, 0, 0);
            S[qt][kt] = __builtin_amdgcn_mfma_f32_16x16x32_bf16(aq[qt][1], bk[1], S[qt][kt], 0, 0, 0);
        }
    }

    const float scale = 0.03125f;   // 1/sqrt(1024)
#pragma unroll
    for (int qt = 0; qt < 2; qt++) {
#pragma unroll
        for (int r = 0; r < 4; r++) {
            int qrow = (wid << 5) + (qt << 4) + ((lane >> 4) << 2) + r;
            const float* mrow = mask + (hmode ? (a << 7) : (qrow << 7));
            float mx = -1e30f;
#pragma unroll
            for (int kt = 0; kt < 8; kt++) {
                float sv = fmaf(S[qt][kt][r], scale, mrow[(kt << 4) + (lane & 15)]);
                S[qt][kt][r] = sv;
                mx = fmaxf(mx, sv);
            }
            mx = fmaxf(mx, __shfl_xor(mx, 1));
            mx = fmaxf(mx, __shfl_xor(mx, 2));
            mx = fmaxf(mx, __shfl_xor(mx, 4));
            mx = fmaxf(mx, __shfl_xor(mx, 8));
            float sum = 0.f;
#pragma unroll
            for (int kt = 0; kt < 8; kt++) {
                float p = __expf(S[qt][kt][r] - mx);
                S[qt][kt][r] = p;
                sum += p;
            }
            sum += __shfl_xor(sum, 1);
            sum += __shfl_xor(sum, 2);
            sum += __shfl_xor(sum, 4);
            sum += __shfl_xor(sum, 8);
            float rinv = 1.0f / sum;
#pragma unroll
            for (int kt = 0; kt < 8; kt++) {
                int kcol = (kt << 4) + (lane & 15);
                int ch = (kcol >> 3) ^ (qrow & 15);
                Pl[(qrow << 7) + (ch << 3) + (kcol & 7)] = bf16u(S[qt][kt][r] * rinv);
            }
        }
    }
    __syncthreads();

    f32x4 O[4][2] = {};
#pragma unroll
    for (int ks = 0; ks < 4; ks++) {
        bf16x8 av[4], bp[2];
#pragma unroll
        for (int dt = 0; dt < 4; dt++) {
            int drow = (dt << 4) + (lane & 15);
            int ch = ((ks << 2) + (lane >> 4)) ^ (drow & 15);
            av[dt] = *(const bf16x8*)&VT[(drow << 7) + (ch << 3)];
        }
#pragma unroll
        for (int qt = 0; qt < 2; qt++) {
            int qrow = (wid << 5) + (qt << 4) + (lane & 15);
            int ch = ((ks << 2) + (lane >> 4)) ^ (qrow & 15);
            bp[qt] = *(const bf16x8*)&Pl[(qrow << 7) + (ch << 3)];
        }
#pragma unroll
        for (int dt = 0; dt < 4; dt++)
#pragma unroll
            for (int qt = 0; qt < 2; qt++)
                O[dt][qt] = __builtin_amdgcn_mfma_f32_16x16x32_bf16(av[dt], bp[qt], O[dt][qt], 0, 0, 0);
    }

    const int cbase = (hmode ? 1024 : 0) + (hd << 6);
#pragma unroll
    for (int dt = 0; dt < 4; dt++)
#pragma unroll
        for (int qt = 0; qt < 2; qt++) {
            int qrow = (wid << 5) + (qt << 4) + (lane & 15);
            int d0 = (dt << 4) + ((lane >> 4) << 2);
            size_t base = ((size_t)(qrow * tmul + tadd) << 11) + cbase + d0;
            ushort4 pk;
            pk.x = bf16u(O[dt][qt][0]);
            pk.y = bf16u(O[dt][qt][1]);
            pk.z = bf16u(O[dt][qt][2]);
            pk.w = bf16u(O[dt][qt][3]);
            *(ushort4*)(cat + base) = pk;
        }
}

extern "C" void kernel_launch(void* const* d_in, const int* in_sizes, int n_in,
                              void* d_out, int out_size, void* d_ws, size_t ws_size,
                              hipStream_t stream)
{
    (void)in_sizes; (void)n_in; (void)out_size; (void)ws_size;
    const float* hidden = (const float*)d_in[0];
    const float* mask   = (const float*)d_in[1];
    const float* cosp   = (const float*)d_in[2];
    const float* sinp   = (const float*)d_in[3];
    const float* Wq     = (const float*)d_in[4];
    const float* Wk     = (const float*)d_in[5];
    const float* Wv     = (const float*)d_in[6];
    const float* Wo     = (const float*)d_in[7];

    char* ws = (char*)d_ws;
    u16* Xb    = (u16*)(ws);                  // 33,554,432 B
    u16* WqkvT = (u16*)(ws + 33554432);       //  6,291,456 B
    u16* cat   = (u16*)(ws);                  // 67,108,864 B (reuse, stream-ordered)
    u16* WoT   = (u16*)(ws + 67108864);       //  4,194,304 B
    u16* qkvb  = (u16*)(ws + 71303168);       // 100,663,296 B

    cvt_x_kernel<<<16384, 256, 0, stream>>>((const float4*)hidden, (ushort4*)Xb, 4194304);

    transp_kernel<<<dim3(32, 32), 256, 0, stream>>>(Wq, WqkvT,               1024, 1024);
    transp_kernel<<<dim3(32, 32), 256, 0, stream>>>(Wk, WqkvT + 1024 * 1024, 1024, 1024);
    transp_kernel<<<dim3(32, 32), 256, 0, stream>>>(Wv, WqkvT + 2048 * 1024, 1024, 1024);
    transp_kernel<<<dim3(32, 64), 256, 0, stream>>>(Wo, WoT, 2048, 1024);

    // fused QKV projection + RoPE: [16384,1024] x [1024,3072]
    gemm8<<<dim3(12, 64), 512, 0, stream>>>(Xb, WqkvT, qkvb, cosp, sinp, 16384, 3072, 1024, 1);

    axial_attn<<<2048, 256, 0, stream>>>(qkvb, mask, cat, 0);
    axial_attn<<<2048, 256, 0, stream>>>(qkvb, mask, cat, 1);

    // output projection: [16384,2048] x [2048,1024] -> fp32
    gemm8<<<dim3(4, 64), 512, 0, stream>>>(cat, WoT, d_out, nullptr, nullptr, 16384, 1024, 2048, 2);
}

// Round 5
// 327.948 us; speedup vs baseline: 1.3511x; 1.1039x over previous
//
#include <hip/hip_runtime.h>

typedef unsigned short u16;
typedef unsigned int   u32;
typedef __bf16 bf16;
typedef bf16  bf16x8 __attribute__((ext_vector_type(8)));
typedef float f32x4  __attribute__((ext_vector_type(4)));

__device__ __forceinline__ u16 bf16u(float f) {
    u32 x = __builtin_bit_cast(u32, f);
    x += 0x7fffu + ((x >> 16) & 1u);   // RNE
    return (u16)(x >> 16);
}

__device__ __forceinline__ void gl_lds16(const void* g, void* l) {
    __builtin_amdgcn_global_load_lds(
        (const __attribute__((address_space(1))) u32*)g,
        (__attribute__((address_space(3))) u32*)l, 16, 0, 0);
}

// ---------------- fp32 -> bf16 convert (vectorized) ----------------
__global__ __launch_bounds__(256) void cvt_x_kernel(const float4* __restrict__ in,
                                                    ushort4* __restrict__ out, int n4) {
    int i = blockIdx.x * 256 + threadIdx.x;
    if (i >= n4) return;
    float4 f = in[i];
    ushort4 o;
    o.x = bf16u(f.x); o.y = bf16u(f.y); o.z = bf16u(f.z); o.w = bf16u(f.w);
    out[i] = o;
}

// ---------------- fp32 W[rows][cols] -> bf16 W^T[cols][rows] ----------------
__global__ __launch_bounds__(256) void transp_kernel(const float* __restrict__ W,
                                                     u16* __restrict__ WT,
                                                     int rows, int cols) {
    __shared__ float t[32][33];
    int bx = blockIdx.x * 32, by = blockIdx.y * 32;
    int x = threadIdx.x & 31, y = threadIdx.x >> 5;
#pragma unroll
    for (int i = 0; i < 32; i += 8)
        t[y + i][x] = W[(size_t)(by + y + i) * cols + bx + x];
    __syncthreads();
#pragma unroll
    for (int i = 0; i < 32; i += 8)
        WT[(size_t)(bx + y + i) * rows + by + x] = bf16u(t[x][y + i]);
}

// ================= 256x256 GEMM, 8-phase schedule (m201 port) ===============
// C[M][N] = A[M][K] * BT[N][K]^T. 512 thr = 8 waves (2M x 4N), wave tile 128x64.
// K-tile 64; iteration = 2 K-tiles = 8 phases. LDS = 2 dbuf x 2 half x
// (128x64) x (A,B) x 2B = 128 KB.
// Stage rotation (Tb=2i+1 buf1, Tc=2i+2 buf0, Td=2i+3 buf1); last reads:
// A-buf0 P3, B-buf0 P2, A-buf1 P7, B-buf1 P6:
//   P1: A(Tb,1)+B(Tb,1) | P3: B(Tc,0)+B(Tc,1) | P4: A(Tc,0) [vmcnt(6) -> Tb landed]
//   P5: A(Tc,1) | P7: B(Td,0) | P8: A(Td,0)   [vmcnt(4) -> Tc landed]
// Last iteration: Tc/Td skipped => P4 uses vmcnt(0).
__device__ __forceinline__ void rd_a(const u16* base, int lane, int ch0, int ch1,
                                     int mh, bf16x8* fa) {
#pragma unroll
    for (int q = 0; q < 4; q++) {
        int off = (((mh << 2) + q) << 10) + ((lane & 15) << 6);
        fa[2 * q]     = *(const bf16x8*)&base[off + ch0];
        fa[2 * q + 1] = *(const bf16x8*)&base[off + ch1];
    }
}
__device__ __forceinline__ void rd_b(const u16* base, int lane, int ch0, int ch1,
                                     int rbase, int nh, bf16x8* fb) {
#pragma unroll
    for (int q = 0; q < 2; q++) {
        int off = rbase + (((nh << 1) + q) << 10) + ((lane & 15) << 6);
        fb[2 * q]     = *(const bf16x8*)&base[off + ch0];
        fb[2 * q + 1] = *(const bf16x8*)&base[off + ch1];
    }
}
__device__ __forceinline__ void mm16(f32x4 (&acc)[8][4], const bf16x8* fa,
                                     const bf16x8* fb, int mh, int nh) {
    __builtin_amdgcn_s_setprio(1);
#pragma unroll
    for (int q = 0; q < 4; q++)
#pragma unroll
        for (int p = 0; p < 2; p++) {
            f32x4 c = acc[(mh << 2) + q][(nh << 1) + p];
            c = __builtin_amdgcn_mfma_f32_16x16x32_bf16(fa[2 * q],     fb[2 * p],     c, 0, 0, 0);
            c = __builtin_amdgcn_mfma_f32_16x16x32_bf16(fa[2 * q + 1], fb[2 * p + 1], c, 0, 0, 0);
            acc[(mh << 2) + q][(nh << 1) + p] = c;
        }
    __builtin_amdgcn_s_setprio(0);
}

#define BAR   __builtin_amdgcn_s_barrier()
#define SB0   __builtin_amdgcn_sched_barrier(0)
#define LGKM0 asm volatile("s_waitcnt lgkmcnt(0)" ::: "memory")
#define VM6   asm volatile("s_waitcnt vmcnt(6)" ::: "memory")
#define VM4   asm volatile("s_waitcnt vmcnt(4)" ::: "memory")
#define VM0   asm volatile("s_waitcnt vmcnt(0)" ::: "memory")

__global__ __launch_bounds__(512, 2) void gemm8(
    const u16* __restrict__ A, const u16* __restrict__ BT, void* __restrict__ Cout,
    const float* __restrict__ cosp, const float* __restrict__ sinp,
    int M, int N, int K, int mode)
{
    __shared__ u16 Al[2][2][8192];   // [dbuf][half][128*64]
    __shared__ u16 Bl[2][2][8192];
    const int tid = threadIdx.x;
    const int wid = tid >> 6, lane = tid & 63;
    const int nx = gridDim.x;
    const int nwg = nx * gridDim.y;
    const int orig = blockIdx.y * nx + blockIdx.x;
    const int vid = (orig & 7) * (nwg >> 3) + (orig >> 3);
    const int m0 = (vid / nx) << 8, n0 = (vid % nx) << 8;
    const int wr = wid >> 2, wc = wid & 3;
    const int wch = wc >> 1, rbB = (wc & 1) << 12;

    // staging: thread covers chunks c=tid and c=512+tid of each 128x64 half.
    // r = c>>3, slot s = c&7; source chunk g = s ^ (r&7) (inverse swizzle on src).
    const int sr = tid >> 3;
    const int sg = (tid & 7) ^ (sr & 7);
    const u16* Asrc = A + (size_t)(m0 + sr) * K + (sg << 3);
    const u16* Bsrc = BT + (size_t)(n0 + sr) * K + (sg << 3);
    const size_t hK   = (size_t)128 * K;
    const size_t h64K = (size_t)64 * K;
    const int db = wid << 9;                 // wave-uniform LDS dest (u16 idx)
    const int nt = K >> 6;                   // number of 64-wide K-tiles

#define STGA(T, h) do { if ((T) < nt) { \
        const u16* _s = Asrc + (size_t)(h) * hK + ((size_t)(T) << 6); \
        gl_lds16(_s,        &Al[(T) & 1][h][db]); \
        gl_lds16(_s + h64K, &Al[(T) & 1][h][4096 + db]); } } while (0)
#define STGB(T, h) do { if ((T) < nt) { \
        const u16* _s = Bsrc + (size_t)(h) * hK + ((size_t)(T) << 6); \
        gl_lds16(_s,        &Bl[(T) & 1][h][db]); \
        gl_lds16(_s + h64K, &Bl[(T) & 1][h][4096 + db]); } } while (0)

    // frag-read swizzled chunk offsets (u16): logical chunk kk*4 + (lane>>4),
    // physical = logical ^ (lane&7)  (row&7 == lane&7 since rows step by 16)
    const int ch0 = (((lane >> 4))     ^ (lane & 7)) << 3;
    const int ch1 = (((lane >> 4) + 4) ^ (lane & 7)) << 3;

    f32x4 acc[8][4] = {};

    // prologue: tile0 fully, then B(1,0), A(1,0) (order = steady-state carry)
    STGA(0, 0); STGA(0, 1); STGB(0, 0); STGB(0, 1);
    STGB(1, 0); STGA(1, 0);
    VM4;                      // tile0 landed; B(1,0),A(1,0) in flight (4 loads)
    BAR; SB0;

    const int nt2 = nt >> 1;
    for (int i = 0; i < nt2; ++i) {
        const int Tb = 2 * i + 1, Tc = 2 * i + 2, Td = 2 * i + 3;
        bf16x8 fa[8], fb[4], fc[4];
        // ---- P1: read A0.mh0 + B0.nh0 | stage A(Tb,1)+B(Tb,1) ----
        rd_a(&Al[0][wr][0], lane, ch0, ch1, 0, fa);
        rd_b(&Bl[0][wch][0], lane, ch0, ch1, rbB, 0, fb);
        STGA(Tb, 1); STGB(Tb, 1);
        BAR; LGKM0; mm16(acc, fa, fb, 0, 0); BAR;
        // ---- P2: read B0.nh1 ----
        rd_b(&Bl[0][wch][0], lane, ch0, ch1, rbB, 1, fc);
        BAR; LGKM0; mm16(acc, fa, fc, 0, 1); BAR;
        // ---- P3: read A0.mh1 | stage B(Tc,0)+B(Tc,1) ----
        rd_a(&Al[0][wr][0], lane, ch0, ch1, 1, fa);
        STGB(Tc, 0); STGB(Tc, 1);
        BAR; LGKM0; mm16(acc, fa, fc, 1, 1); BAR;
        // ---- P4: stage A(Tc,0); publish buf1 (Tb) ----
        STGA(Tc, 0);
        BAR; LGKM0; mm16(acc, fa, fb, 1, 0);
        if (i + 1 < nt2) { VM6; } else { VM0; }
        BAR; SB0;
        // ---- P5: read A1.mh0 + B1.nh0 | stage A(Tc,1) ----
        rd_a(&Al[1][wr][0], lane, ch0, ch1, 0, fa);
        rd_b(&Bl[1][wch][0], lane, ch0, ch1, rbB, 0, fb);
        STGA(Tc, 1);
        BAR; LGKM0; mm16(acc, fa, fb, 0, 0); BAR;
        // ---- P6: read B1.nh1 ----
        rd_b(&Bl[1][wch][0], lane, ch0, ch1, rbB, 1, fc);
        BAR; LGKM0; mm16(acc, fa, fc, 0, 1); BAR;
        // ---- P7: read A1.mh1 | stage B(Td,0) ----
        rd_a(&Al[1][wr][0], lane, ch0, ch1, 1, fa);
        STGB(Td, 0);
        BAR; LGKM0; mm16(acc, fa, fc, 1, 1); BAR;
        // ---- P8: stage A(Td,0); publish buf0 (Tc) ----
        STGA(Td, 0);
        BAR; LGKM0; mm16(acc, fa, fb, 1, 0);
        VM4;
        BAR; SB0;
    }
#undef STGA
#undef STGB

    const int colbase = n0 + (wc << 6) + (lane & 15);
    if (mode == 2) {
        float* C = (float*)Cout;
#pragma unroll
        for (int mi = 0; mi < 8; mi++)
#pragma unroll
            for (int r = 0; r < 4; r++) {
                int m = m0 + (wr << 7) + (mi << 4) + ((lane >> 4) << 2) + r;
                float* row = C + (size_t)m * N + colbase;
#pragma unroll
                for (int ni = 0; ni < 4; ni++) row[ni << 4] = acc[mi][ni][r];
            }
    } else if (n0 < 2048) {                   // fused QKV: RoPE region (Q and K)
        u16* C = (u16*)Cout;
#pragma unroll
        for (int mi = 0; mi < 8; mi++)
#pragma unroll
            for (int r = 0; r < 4; r++) {
                int m = m0 + (wr << 7) + (mi << 4) + ((lane >> 4) << 2) + r;
                const float* cb = cosp + ((size_t)m << 6);
                const float* sb = sinp + ((size_t)m << 6);
                u16* row = C + (size_t)m * N + colbase;
#pragma unroll
                for (int ni = 0; ni < 4; ni++) {
                    int d = (ni << 4) + (lane & 15);   // head-dim pos (0..63)
                    float c = cb[d], s = sb[d];
                    float v0 = acc[mi][ni][r];
                    float vr = acc[mi][ni ^ 2][r];     // d +/- 32 partner
                    float o = fmaf(v0, c, (ni < 2 ? -vr : vr) * s);
                    row[ni << 4] = bf16u(o);
                }
            }
    } else {                                  // V region: plain bf16
        u16* C = (u16*)Cout;
#pragma unroll
        for (int mi = 0; mi < 8; mi++)
#pragma unroll
            for (int r = 0; r < 4; r++) {
                int m = m0 + (wr << 7) + (mi << 4) + ((lane >> 4) << 2) + r;
                u16* row = C + (size_t)m * N + colbase;
#pragma unroll
                for (int ni = 0; ni < 4; ni++) row[ni << 4] = bf16u(acc[mi][ni][r]);
            }
    }
}

// ---------------- axial attention, one (line, head) per block ----------------
__global__ __launch_bounds__(256) void axial_attn(
    const u16* __restrict__ qkv, const float* __restrict__ mask,
    u16* __restrict__ cat, int hmode)
{
    __shared__ u16 Kl[128 * 64];    // XOR-swizzled 16B chunks (^ row&7)
    __shared__ u16 VT[64 * 128];    // V^T, swizzled (^ d&15)
    __shared__ u16 Pl[128 * 128];   // P (q-major), swizzled (^ q&15)
    const int orig = blockIdx.x;
    const int b = (orig & 7) * 256 + (orig >> 3);   // nwg = 2048
    const int a = b >> 4, hd = b & 15;
    const int tid = threadIdx.x, wid = tid >> 6, lane = tid & 63;
    const int tmul = hmode ? 128 : 1;
    const int tadd = hmode ? a : (a << 7);
    const size_t hoff = (size_t)hd << 6;

#pragma unroll
    for (int c = 0; c < 4; c++) {
        int row = (wid << 5) + (c << 3) + (lane >> 3);
        int sc = (lane & 7) ^ (row & 7);
        gl_lds16(qkv + (size_t)(row * tmul + tadd) * 3072 + 1024 + hoff + (sc << 3),
                 &Kl[((wid << 5) + (c << 3)) << 6]);
    }
#pragma unroll
    for (int i = 0; i < 4; i++) {
        int cid = tid + (i << 8);
        int j = cid >> 3;
        int d0 = (cid & 7) << 3;
        uint4 raw = *(const uint4*)(qkv + (size_t)(j * tmul + tadd) * 3072 + 2048 + hoff + d0);
        const u16* e = (const u16*)&raw;
#pragma unroll
        for (int t = 0; t < 8; t++) {
            int d = d0 + t;
            VT[(d << 7) + (((j >> 3) ^ (d & 15)) << 3) + (j & 7)] = e[t];
        }
    }
    bf16x8 aq[2][2];
#pragma unroll
    for (int qt = 0; qt < 2; qt++)
#pragma unroll
        for (int ks = 0; ks < 2; ks++) {
            int row = (wid << 5) + (qt << 4) + (lane & 15);
            aq[qt][ks] = *(const bf16x8*)(qkv + (size_t)(row * tmul + tadd) * 3072 + hoff
                                          + (ks << 5) + ((lane >> 4) << 3));
        }
    __syncthreads();

    f32x4 S[2][8] = {};
#pragma unroll
    for (int kt = 0; kt < 8; kt++) {
        bf16x8 bk[2];
#pragma unroll
        for (int ks = 0; ks < 2; ks++) {
            int row = (kt << 4) + (lane & 15);
            int ch = ((ks << 2) + (lane >> 4)) ^ (row & 7);
            bk[ks] = *(const bf16x8*)&Kl[(row << 6) + (ch << 3)];
        }
#pragma unroll
        for (int qt = 0; qt < 2; qt++) {
            S[qt][kt] = __builtin_amdgcn_mfma_f32_16x16x32_bf16(aq[qt][0], bk[0], S[qt][kt], 0, 0, 0);
            S[qt][kt] = __builtin_amdgcn_mfma_f32_16x16x32_bf16(aq[qt][1], bk[1], S[qt][kt], 0, 0, 0);
        }
    }

    const float scale = 0.03125f;   // 1/sqrt(1024)
#pragma unroll
    for (int qt = 0; qt < 2; qt++) {
#pragma unroll
        for (int r = 0; r < 4; r++) {
            int qrow = (wid << 5) + (qt << 4) + ((lane >> 4) << 2) + r;
            const float* mrow = mask + (hmode ? (a << 7) : (qrow << 7));
            float mx = -1e30f;
#pragma unroll
            for (int kt = 0; kt < 8; kt++) {
                float sv = fmaf(S[qt][kt][r], scale, mrow[(kt << 4) + (lane & 15)]);
                S[qt][kt][r] = sv;
                mx = fmaxf(mx, sv);
            }
            mx = fmaxf(mx, __shfl_xor(mx, 1));
            mx = fmaxf(mx, __shfl_xor(mx, 2));
            mx = fmaxf(mx, __shfl_xor(mx, 4));
            mx = fmaxf(mx, __shfl_xor(mx, 8));
            float sum = 0.f;
#pragma unroll
            for (int kt = 0; kt < 8; kt++) {
                float p = __expf(S[qt][kt][r] - mx);
                S[qt][kt][r] = p;
                sum += p;
            }
            sum += __shfl_xor(sum, 1);
            sum += __shfl_xor(sum, 2);
            sum += __shfl_xor(sum, 4);
            sum += __shfl_xor(sum, 8);
            float rinv = 1.0f / sum;
#pragma unroll
            for (int kt = 0; kt < 8; kt++) {
                int kcol = (kt << 4) + (lane & 15);
                int ch = (kcol >> 3) ^ (qrow & 15);
                Pl[(qrow << 7) + (ch << 3) + (kcol & 7)] = bf16u(S[qt][kt][r] * rinv);
            }
        }
    }
    __syncthreads();

    f32x4 O[4][2] = {};
#pragma unroll
    for (int ks = 0; ks < 4; ks++) {
        bf16x8 av[4], bp[2];
#pragma unroll
        for (int dt = 0; dt < 4; dt++) {
            int drow = (dt << 4) + (lane & 15);
            int ch = ((ks << 2) + (lane >> 4)) ^ (drow & 15);
            av[dt] = *(const bf16x8*)&VT[(drow << 7) + (ch << 3)];
        }
#pragma unroll
        for (int qt = 0; qt < 2; qt++) {
            int qrow = (wid << 5) + (qt << 4) + (lane & 15);
            int ch = ((ks << 2) + (lane >> 4)) ^ (qrow & 15);
            bp[qt] = *(const bf16x8*)&Pl[(qrow << 7) + (ch << 3)];
        }
#pragma unroll
        for (int dt = 0; dt < 4; dt++)
#pragma unroll
            for (int qt = 0; qt < 2; qt++)
                O[dt][qt] = __builtin_amdgcn_mfma_f32_16x16x32_bf16(av[dt], bp[qt], O[dt][qt], 0, 0, 0);
    }

    const int cbase = (hmode ? 1024 : 0) + (hd << 6);
#pragma unroll
    for (int dt = 0; dt < 4; dt++)
#pragma unroll
        for (int qt = 0; qt < 2; qt++) {
            int qrow = (wid << 5) + (qt << 4) + (lane & 15);
            int d0 = (dt << 4) + ((lane >> 4) << 2);
            size_t base = ((size_t)(qrow * tmul + tadd) << 11) + cbase + d0;
            ushort4 pk;
            pk.x = bf16u(O[dt][qt][0]);
            pk.y = bf16u(O[dt][qt][1]);
            pk.z = bf16u(O[dt][qt][2]);
            pk.w = bf16u(O[dt][qt][3]);
            *(ushort4*)(cat + base) = pk;
        }
}

extern "C" void kernel_launch(void* const* d_in, const int* in_sizes, int n_in,
                              void* d_out, int out_size, void* d_ws, size_t ws_size,
                              hipStream_t stream)
{
    (void)in_sizes; (void)n_in; (void)out_size; (void)ws_size;
    const float* hidden = (const float*)d_in[0];
    const float* mask   = (const float*)d_in[1];
    const float* cosp   = (const float*)d_in[2];
    const float* sinp   = (const float*)d_in[3];
    const float* Wq     = (const float*)d_in[4];
    const float* Wk     = (const float*)d_in[5];
    const float* Wv     = (const float*)d_in[6];
    const float* Wo     = (const float*)d_in[7];

    char* ws = (char*)d_ws;
    u16* Xb    = (u16*)(ws);                  // 33,554,432 B
    u16* WqkvT = (u16*)(ws + 33554432);       //  6,291,456 B
    u16* cat   = (u16*)(ws);                  // 67,108,864 B (reuse, stream-ordered)
    u16* WoT   = (u16*)(ws + 67108864);       //  4,194,304 B
    u16* qkvb  = (u16*)(ws + 71303168);       // 100,663,296 B

    cvt_x_kernel<<<16384, 256, 0, stream>>>((const float4*)hidden, (ushort4*)Xb, 4194304);

    transp_kernel<<<dim3(32, 32), 256, 0, stream>>>(Wq, WqkvT,               1024, 1024);
    transp_kernel<<<dim3(32, 32), 256, 0, stream>>>(Wk, WqkvT + 1024 * 1024, 1024, 1024);
    transp_kernel<<<dim3(32, 32), 256, 0, stream>>>(Wv, WqkvT + 2048 * 1024, 1024, 1024);
    transp_kernel<<<dim3(32, 64), 256, 0, stream>>>(Wo, WoT, 2048, 1024);

    // fused QKV projection + RoPE: [16384,1024] x [1024,3072]
    gemm8<<<dim3(12, 64), 512, 0, stream>>>(Xb, WqkvT, qkvb, cosp, sinp, 16384, 3072, 1024, 1);

    axial_attn<<<2048, 256, 0, stream>>>(qkvb, mask, cat, 0);
    axial_attn<<<2048, 256, 0, stream>>>(qkvb, mask, cat, 1);

    // output projection: [16384,2048] x [2048,1024] -> fp32
    gemm8<<<dim3(4, 64), 512, 0, stream>>>(cat, WoT, d_out, nullptr, nullptr, 16384, 1024, 2048, 2);
}